// Round 2
// baseline (32.887 us; speedup 1.0000x reference)
//
#include <hip/hip_runtime.h>
#include <math.h>

#define BATCH 2048
#define IN_DIM 784
#define NQ 14
#define NF 105
#define NC 10
#define CHUNKS 196   // IN_DIM / 4 float4 chunks per row

// Analytic collapse of the quantum feature map:
//   angles  = tanh(x @ proj_w.T + proj_b) * pi          (B, 14)
//   c_q     = cos(angle_q)
//   final bit k of circuit = XOR of initial bits {k, k-2, k-4, ...}
//   <Z_i>    = prod_{q in S_i} c_q,  S_i = {i, i-2, ...}
//   <Z_i Z_j>= prod over S_i XOR S_j
//   out      = feats @ cls_w.T + cls_b
// Mask closed form: zm(q) = (0x1555 << (q&1)) & ((2u<<q)-1)

__device__ __forceinline__ unsigned zmask(int q) {
    return (0x1555u << (q & 1)) & ((2u << q) - 1u);
}

// One block = one batch row. 256 threads (4 waves) split the 784-long dot
// products; tiny LDS transpose finishes the reduction; wave 0 does the
// transcendentals + feature/classifier phase.
__global__ __launch_bounds__(256) void qfm_kernel(
    const float* __restrict__ x,
    const float* __restrict__ pw,
    const float* __restrict__ pb,
    const float* __restrict__ cw,
    const float* __restrict__ cb,
    float* __restrict__ out)
{
    const int row  = (int)blockIdx.x;
    const int t    = (int)threadIdx.x;
    const int lane = t & 63;
    const int wv   = t >> 6;

    __shared__ __align__(16) float part[NQ][4];  // per-wave partials
    __shared__ float c_sh[NQ];

    // ---- each thread owns one float4 chunk of the x row ----
    const float4* xr4 = reinterpret_cast<const float4*>(x + (size_t)row * IN_DIM);
    float4 xv = make_float4(0.f, 0.f, 0.f, 0.f);
    if (t < CHUNKS) xv = xr4[t];

    // ---- 14 partial dots (one pw float4 load each), independent chains ----
    float acc[NQ];
#pragma unroll
    for (int q = 0; q < NQ; ++q) acc[q] = 0.f;
#pragma unroll
    for (int q = 0; q < NQ; ++q) {
        if (t < CHUNKS) {
            float4 w4 = reinterpret_cast<const float4*>(pw + (size_t)q * IN_DIM)[t];
            acc[q] = xv.x * w4.x + xv.y * w4.y + xv.z * w4.z + xv.w * w4.w;
        }
    }

    // ---- intra-wave butterfly per q (independent 6-deep chains) ----
#pragma unroll
    for (int q = 0; q < NQ; ++q) {
        float a = acc[q];
#pragma unroll
        for (int s = 32; s > 0; s >>= 1) a += __shfl_xor(a, s, 64);
        if (lane == 0) part[q][wv] = a;
    }
    __syncthreads();

    // ---- finish reduction + transcendentals (lanes 0..13 of wave 0) ----
    if (t < NQ) {
        float4 p4 = reinterpret_cast<const float4*>(part)[t];
        float s = (p4.x + p4.y) + (p4.z + p4.w);
        float theta = tanhf(s + pb[t]) * 3.14159265358979323846f;
        c_sh[t] = cosf(theta);
    }
    __syncthreads();

    // ---- feature + classifier phase: wave 0 only ----
    if (wv == 0) {
        float c[NQ];
#pragma unroll
        for (int q = 0; q < NQ; ++q) c[q] = c_sh[q];

        float acc_out[NC];
#pragma unroll
        for (int k = 0; k < NC; ++k) acc_out[k] = 0.f;

#pragma unroll
        for (int rep = 0; rep < 2; ++rep) {
            const int f = lane + rep * 64;
            if (f < NF) {
                unsigned m;
                if (f < NQ) {
                    m = zmask(f);
                } else {
                    int g = f - NQ;
                    int i = 0;
                    while (g >= NQ - 1 - i) { g -= NQ - 1 - i; ++i; }
                    const int j = i + 1 + g;
                    m = zmask(i) ^ zmask(j);
                }
                float prod = 1.f;
#pragma unroll
                for (int q = 0; q < NQ; ++q) {
                    const float mult = ((m >> q) & 1u) ? c[q] : 1.0f;
                    prod *= mult;
                }
#pragma unroll
                for (int k = 0; k < NC; ++k)
                    acc_out[k] += cw[k * NF + f] * prod;
            }
        }

        // reduce 10 outputs across the wave, lane 0 writes
#pragma unroll
        for (int k = 0; k < NC; ++k) {
            float a = acc_out[k];
#pragma unroll
            for (int s = 32; s > 0; s >>= 1) a += __shfl_xor(a, s, 64);
            if (lane == 0) out[(size_t)row * NC + k] = a + cb[k];
        }
    }
}

extern "C" void kernel_launch(void* const* d_in, const int* in_sizes, int n_in,
                              void* d_out, int out_size, void* d_ws, size_t ws_size,
                              hipStream_t stream) {
    const float* x  = (const float*)d_in[0];
    const float* pw = (const float*)d_in[1];
    const float* pb = (const float*)d_in[2];
    const float* cw = (const float*)d_in[3];
    const float* cb = (const float*)d_in[4];
    float* out = (float*)d_out;

    qfm_kernel<<<dim3(BATCH), dim3(256), 0, stream>>>(x, pw, pb, cw, cb, out);
}

// Round 3
// 15.225 us; speedup vs baseline: 2.1601x; 2.1601x over previous
//
#include <hip/hip_runtime.h>
#include <math.h>

#define BATCH 2048
#define IN_DIM 784
#define NQ 14
#define NF 105
#define NC 10

// Analytic collapse of the quantum feature map:
//   angles  = tanh(x @ proj_w.T + proj_b) * pi
//   c_q     = cos(angle_q)
//   final bit k of circuit = XOR of initial bits {k, k-2, k-4, ...}
//   <Z_i>    = prod_{q in S_i} c_q;  <Z_i Z_j> = prod over S_i XOR S_j
//   out      = feats @ cls_w.T + cls_b
// zmask(q) = (0x1555 << (q&1)) & ((2u<<q)-1)
//
// R2: R0 structure (1 wave/row, no LDS/barriers) + fast transcendentals
// (tanh via v_exp+v_rcp, cos(pi*t) via v_cos) + branch-free (i,j) decode.

__device__ __forceinline__ unsigned zmask(int q) {
    return (0x1555u << (q & 1)) & ((2u << q) - 1u);
}

__global__ __launch_bounds__(256) void qfm_kernel(
    const float* __restrict__ x,
    const float* __restrict__ pw,
    const float* __restrict__ pb,
    const float* __restrict__ cw,
    const float* __restrict__ cb,
    float* __restrict__ out)
{
    const int wave = (int)((blockIdx.x * blockDim.x + threadIdx.x) >> 6);
    const int lane = (int)(threadIdx.x & 63);
    if (wave >= BATCH) return;

    // ---- load x row: 196 float4 chunks, 3 per lane + remainder ----
    const float4* xr4 = reinterpret_cast<const float4*>(x + (size_t)wave * IN_DIM);
    float4 xv[3];
#pragma unroll
    for (int k = 0; k < 3; ++k) xv[k] = xr4[lane + 64 * k];
    float4 xrem = make_float4(0.f, 0.f, 0.f, 0.f);
    if (lane < 4) xrem = xr4[192 + lane];

    // ---- 14 projection partial dots (independent chains) ----
    float acc[NQ];
#pragma unroll
    for (int q = 0; q < NQ; ++q) {
        const float4* wr4 = reinterpret_cast<const float4*>(pw + (size_t)q * IN_DIM);
        float a = 0.f;
#pragma unroll
        for (int k = 0; k < 3; ++k) {
            float4 wv = wr4[lane + 64 * k];
            a += xv[k].x * wv.x + xv[k].y * wv.y + xv[k].z * wv.z + xv[k].w * wv.w;
        }
        if (lane < 4) {
            float4 wv = wr4[192 + lane];
            a += xrem.x * wv.x + xrem.y * wv.y + xrem.z * wv.z + xrem.w * wv.w;
        }
        acc[q] = a;
    }

    // ---- wave butterflies (14 independent 6-deep chains) ----
#pragma unroll
    for (int q = 0; q < NQ; ++q) {
        float a = acc[q];
#pragma unroll
        for (int s = 32; s > 0; s >>= 1) a += __shfl_xor(a, s, 64);
        acc[q] = a;
    }

    // ---- fast cos(pi * tanh(a)): ~6 VALU ops per q, 14 independent chains ----
    float c[NQ];
#pragma unroll
    for (int q = 0; q < NQ; ++q) {
        const float a = acc[q] + pb[q];
        const float e = __expf(2.0f * a);                       // e^{2a}
        const float r = __builtin_amdgcn_rcpf(e + 1.0f);        // 1/(e^{2a}+1)
        const float t = fmaf(-2.0f, r, 1.0f);                   // tanh(a)
        c[q] = __cosf(3.14159265358979323846f * t);             // cos(pi*tanh)
    }

    // ---- features: lane handles f = lane and f = lane + 64 ----
    float acc_out[NC];
#pragma unroll
    for (int k = 0; k < NC; ++k) acc_out[k] = 0.f;

#pragma unroll
    for (int rep = 0; rep < 2; ++rep) {
        const int f = lane + rep * 64;
        if (f < NF) {
            unsigned m;
            if (f < NQ) {
                m = zmask(f);
            } else {
                // branch-free triangular decode: g -> (i, j)
                const int g = f - NQ;                           // 0..90
                const float sq = __builtin_amdgcn_sqrtf(182.25f - 2.0f * (float)g);
                const int i = (int)(13.5f - sq + 1.0e-4f);      // exact at boundaries
                const int j = i + 1 + g - (i * (27 - i)) / 2;
                m = zmask(i) ^ zmask(j);
            }
            float prod = 1.f;
#pragma unroll
            for (int q = 0; q < NQ; ++q) {
                const float mult = ((m >> q) & 1u) ? c[q] : 1.0f;
                prod *= mult;
            }
#pragma unroll
            for (int k = 0; k < NC; ++k)
                acc_out[k] += cw[k * NF + f] * prod;
        }
    }

    // ---- reduce 10 outputs across the wave; lanes 0..9 write coalesced ----
    float myout = 0.f;
#pragma unroll
    for (int k = 0; k < NC; ++k) {
        float a = acc_out[k];
#pragma unroll
        for (int s = 32; s > 0; s >>= 1) a += __shfl_xor(a, s, 64);
        if (lane == k) myout = a + cb[k];
    }
    if (lane < NC) out[(size_t)wave * NC + lane] = myout;
}

extern "C" void kernel_launch(void* const* d_in, const int* in_sizes, int n_in,
                              void* d_out, int out_size, void* d_ws, size_t ws_size,
                              hipStream_t stream) {
    const float* x  = (const float*)d_in[0];
    const float* pw = (const float*)d_in[1];
    const float* pb = (const float*)d_in[2];
    const float* cw = (const float*)d_in[3];
    const float* cb = (const float*)d_in[4];
    float* out = (float*)d_out;

    qfm_kernel<<<dim3(BATCH / 4), dim3(256), 0, stream>>>(x, pw, pb, cw, cb, out);
}

// Round 5
// 13.218 us; speedup vs baseline: 2.4881x; 1.1518x over previous
//
#include <hip/hip_runtime.h>
#include <math.h>

#define BATCH 2048
#define IN_DIM 784
#define NQ 14
#define NF 105
#define NC 10

// Analytic collapse of the quantum feature map:
//   angles  = tanh(x @ proj_w.T + proj_b) * pi
//   c_q     = cos(angle_q)
//   final bit k of circuit = XOR of initial bits {k, k-2, k-4, ...}
//   <Z_i>    = prod_{q in S_i} c_q;  <Z_i Z_j> = prod over S_i XOR S_j
//   out      = feats @ cls_w.T + cls_b
// zmask(q) = (0x1555 << (q&1)) & ((2u<<q)-1)
//
// R4: same as R3 (VALU DPP butterflies replace ds_bpermute reduction trees)
// with the dpp ctrl passed as a template parameter -- the builtin requires a
// compile-time-constant control field at each call site.

__device__ __forceinline__ unsigned zmask(int q) {
    return (0x1555u << (q & 1)) & ((2u << q) - 1u);
}

template <int CTRL>
__device__ __forceinline__ float dppadd(float x) {
    // x + dpp_mov(x, CTRL); all rows/banks enabled, bound_ctrl=1 (unused src->0)
    return x + __int_as_float(__builtin_amdgcn_update_dpp(
        0, __float_as_int(x), CTRL, 0xF, 0xF, true));
}

__device__ __forceinline__ float wave_allreduce(float x, int xor32addr) {
    x = dppadd<0xB1>(x);   // quad_perm(1,0,3,2)  : + lane^1
    x = dppadd<0x4E>(x);   // quad_perm(2,3,0,1)  : + lane^2
    x = dppadd<0x141>(x);  // row_half_mirror     : + lane^4 (4-groups uniform)
    x = dppadd<0x140>(x);  // row_mirror          : + lane^8 (8-groups uniform)
    // + lane^16 within each 32-lane group
    x = x + __int_as_float(__builtin_amdgcn_ds_swizzle(__float_as_int(x), 0x401F));
#if __has_builtin(__builtin_amdgcn_permlane32_swap)
    {
        typedef unsigned u2v __attribute__((ext_vector_type(2)));
        u2v r = __builtin_amdgcn_permlane32_swap(
            (unsigned)__float_as_int(x), (unsigned)__float_as_int(x), false, false);
        // r[0][l] + r[1][l] == x[l & ~32] + x[l | 32]  (robust to half-assignment)
        x = __int_as_float((int)r[0]) + __int_as_float((int)r[1]);
    }
#else
    x = x + __int_as_float(__builtin_amdgcn_ds_bpermute(xor32addr, __float_as_int(x)));
#endif
    return x;
}

__global__ __launch_bounds__(256) void qfm_kernel(
    const float* __restrict__ x,
    const float* __restrict__ pw,
    const float* __restrict__ pb,
    const float* __restrict__ cw,
    const float* __restrict__ cb,
    float* __restrict__ out)
{
    const int wave = (int)((blockIdx.x * blockDim.x + threadIdx.x) >> 6);
    const int lane = (int)(threadIdx.x & 63);
    const int xor32addr = ((lane ^ 32) << 2);   // ds_bpermute byte addr (fallback)

    // ---- load x row: 196 float4 chunks, 3 per lane + remainder ----
    const float4* xr4 = reinterpret_cast<const float4*>(x + (size_t)wave * IN_DIM);
    float4 xv[3];
#pragma unroll
    for (int k = 0; k < 3; ++k) xv[k] = xr4[lane + 64 * k];
    float4 xrem = make_float4(0.f, 0.f, 0.f, 0.f);
    if (lane < 4) xrem = xr4[192 + lane];

    // ---- 14 projection partial dots (independent chains) ----
    float acc[NQ];
#pragma unroll
    for (int q = 0; q < NQ; ++q) {
        const float4* wr4 = reinterpret_cast<const float4*>(pw + (size_t)q * IN_DIM);
        float a = 0.f;
#pragma unroll
        for (int k = 0; k < 3; ++k) {
            float4 wv = wr4[lane + 64 * k];
            a += xv[k].x * wv.x + xv[k].y * wv.y + xv[k].z * wv.z + xv[k].w * wv.w;
        }
        if (lane < 4) {
            float4 wv = wr4[192 + lane];
            a += xrem.x * wv.x + xrem.y * wv.y + xrem.z * wv.z + xrem.w * wv.w;
        }
        acc[q] = a;
    }

    // ---- wave allreduce per q: VALU butterflies (was 84 ds_bpermute) ----
#pragma unroll
    for (int q = 0; q < NQ; ++q) acc[q] = wave_allreduce(acc[q], xor32addr);

    // ---- fast cos(pi * tanh(a)) ----
    float c[NQ];
#pragma unroll
    for (int q = 0; q < NQ; ++q) {
        const float a = acc[q] + pb[q];
        const float e = __expf(2.0f * a);                       // e^{2a}
        const float r = __builtin_amdgcn_rcpf(e + 1.0f);        // 1/(e^{2a}+1)
        const float t = fmaf(-2.0f, r, 1.0f);                   // tanh(a)
        c[q] = __cosf(3.14159265358979323846f * t);             // cos(pi*tanh)
    }

    // ---- features: lane handles f = lane and f = lane + 64 ----
    float acc_out[NC];
#pragma unroll
    for (int k = 0; k < NC; ++k) acc_out[k] = 0.f;

#pragma unroll
    for (int rep = 0; rep < 2; ++rep) {
        const int f = lane + rep * 64;
        if (f < NF) {
            unsigned m;
            if (f < NQ) {
                m = zmask(f);
            } else {
                // branch-free triangular decode: g -> (i, j)
                const int g = f - NQ;                           // 0..90
                const float sq = __builtin_amdgcn_sqrtf(182.25f - 2.0f * (float)g);
                const int i = (int)(13.5f - sq + 1.0e-4f);      // exact at boundaries
                const int j = i + 1 + g - (i * (27 - i)) / 2;
                m = zmask(i) ^ zmask(j);
            }
            float prod = 1.f;
#pragma unroll
            for (int q = 0; q < NQ; ++q) {
                const float mult = ((m >> q) & 1u) ? c[q] : 1.0f;
                prod *= mult;
            }
#pragma unroll
            for (int k = 0; k < NC; ++k)
                acc_out[k] += cw[k * NF + f] * prod;
        }
    }

    // ---- 10 output reductions (VALU trees); lanes 0..9 write coalesced ----
    float myout = 0.f;
#pragma unroll
    for (int k = 0; k < NC; ++k) {
        const float a = wave_allreduce(acc_out[k], xor32addr);
        if (lane == k) myout = a + cb[k];
    }
    if (lane < NC) out[(size_t)wave * NC + lane] = myout;
}

extern "C" void kernel_launch(void* const* d_in, const int* in_sizes, int n_in,
                              void* d_out, int out_size, void* d_ws, size_t ws_size,
                              hipStream_t stream) {
    const float* x  = (const float*)d_in[0];
    const float* pw = (const float*)d_in[1];
    const float* pb = (const float*)d_in[2];
    const float* cw = (const float*)d_in[3];
    const float* cb = (const float*)d_in[4];
    float* out = (float*)d_out;

    qfm_kernel<<<dim3(BATCH / 4), dim3(256), 0, stream>>>(x, pw, pb, cw, cb, out);
}